// Round 2
// baseline (286.559 us; speedup 1.0000x reference)
//
#include <hip/hip_runtime.h>

// Problem constants (from reference)
#define D_H     512
#define D_MODEL 2048
#define B_      4
#define T_      4096
// T_*D_MODEL = 2^23  (for the >>23 / &2047 index tricks below)

// Native clang vectors (work with __builtin_nontemporal_*; same layout as float4/float2)
typedef float vfloat4 __attribute__((ext_vector_type(4)));
typedef float vfloat2 __attribute__((ext_vector_type(2)));

// out[b][j:j+2] += sum_{k in slice} x[b][k] * W[k][j:j+2]   for all b in [0,4)
// Each thread owns TWO consecutive output columns -> float2 W loads (8 B/lane,
// 512 B per wave per instr) to double in-flight bytes vs the scalar version
// (latency-bound fix: ~8 KiB -> ~16 KiB outstanding per CU).
// x: (4 x K) fp32; W: (K x N) fp32 row-major; out: (4 x N) fp32 (pre-zeroed)
template <int KCHUNK>
__global__ __launch_bounds__(256) void gemv4_splitk_v2(
        const float* __restrict__ x,
        const float* __restrict__ W,
        float* __restrict__ out,
        int K, int N) {
    __shared__ float xs[4][KCHUNK];
    const int tid = threadIdx.x;
    const int j2  = (blockIdx.x * blockDim.x + tid) * 2;  // column pair base
    const int k0  = blockIdx.y * KCHUNK;                  // K-slice start

    for (int i = tid; i < 4 * KCHUNK; i += blockDim.x) {
        int b = i / KCHUNK, k = i - b * KCHUNK;
        xs[b][k] = x[b * K + k0 + k];
    }
    __syncthreads();

    vfloat2 a0 = {0.f, 0.f}, a1 = {0.f, 0.f}, a2 = {0.f, 0.f}, a3 = {0.f, 0.f};
    const float* Wp = W + (long)k0 * N + j2;
#pragma unroll 8
    for (int k = 0; k < KCHUNK; ++k) {
        vfloat2 w = *reinterpret_cast<const vfloat2*>(Wp + (long)k * N);
        float x0 = xs[0][k], x1 = xs[1][k], x2 = xs[2][k], x3 = xs[3][k];
        a0.x = fmaf(x0, w.x, a0.x);  a0.y = fmaf(x0, w.y, a0.y);
        a1.x = fmaf(x1, w.x, a1.x);  a1.y = fmaf(x1, w.y, a1.y);
        a2.x = fmaf(x2, w.x, a2.x);  a2.y = fmaf(x2, w.y, a2.y);
        a3.x = fmaf(x3, w.x, a3.x);  a3.y = fmaf(x3, w.y, a3.y);
    }
    atomicAdd(&out[0 * N + j2],     a0.x);
    atomicAdd(&out[0 * N + j2 + 1], a0.y);
    atomicAdd(&out[1 * N + j2],     a1.x);
    atomicAdd(&out[1 * N + j2 + 1], a1.y);
    atomicAdd(&out[2 * N + j2],     a2.x);
    atomicAdd(&out[2 * N + j2 + 1], a2.y);
    atomicAdd(&out[3 * N + j2],     a3.x);
    atomicAdd(&out[3 * N + j2 + 1], a3.y);
}

// out[b,t,:] = lh[b,t,:] + sigmoid(gate) * r[b,:]
// Grid-stride with 2048 blocks (G11): 16 vfloat4 iterations/thread = 256 B/thread,
// amortizing gate load / sigmoid / index math and avoiding 32K-block dispatch cost.
// lh/out are zero-reuse streams -> nontemporal; r is 32 KB -> L1/L2-resident.
__global__ __launch_bounds__(256) void broadcast_add(
        const vfloat4* __restrict__ lh,
        const float* __restrict__ r,
        const float* __restrict__ gate,
        vfloat4* __restrict__ out,
        long nchunks) {
    float g = gate[0];
    float s = 1.0f / (1.0f + __expf(-g));

    const long stride = (long)gridDim.x * blockDim.x;
    for (long i = (long)blockIdx.x * blockDim.x + threadIdx.x;
         i < nchunks; i += stride) {
        long e0 = i * 4;
        int  b  = (int)(e0 >> 23);             // / (T_*D_MODEL)
        int  d  = (int)(e0 & (D_MODEL - 1));   // col within row (4-aligned)

        vfloat4 rv = *reinterpret_cast<const vfloat4*>(r + b * D_MODEL + d);
        vfloat4 v  = __builtin_nontemporal_load(lh + i);

        vfloat4 o;
        o.x = fmaf(s, rv.x, v.x);
        o.y = fmaf(s, rv.y, v.y);
        o.z = fmaf(s, rv.z, v.z);
        o.w = fmaf(s, rv.w, v.w);
        __builtin_nontemporal_store(o, out + i);
    }
}

extern "C" void kernel_launch(void* const* d_in, const int* in_sizes, int n_in,
                              void* d_out, int out_size, void* d_ws, size_t ws_size,
                              hipStream_t stream) {
    const float* lh    = (const float*)d_in[0];
    const float* zH    = (const float*)d_in[1];
    const float* W_mem = (const float*)d_in[2];
    // d_in[3] = W_q, d_in[4] = W_k  -- provably unused: softmax over a
    // length-1 axis is identically 1, so output is independent of Q and K.
    const float* W_v   = (const float*)d_in[5];
    const float* W_o   = (const float*)d_in[6];
    const float* gate  = (const float*)d_in[7];
    float* out = (float*)d_out;

    // fp32 workspace: mem(4 x D), V(4 x D), r(4 x D)
    float* mem = (float*)d_ws;
    float* V   = mem + B_ * D_MODEL;
    float* r   = V   + B_ * D_MODEL;
    (void)hipMemsetAsync(d_ws, 0, (size_t)3 * B_ * D_MODEL * sizeof(float), stream);

    dim3 blk(256);

    // Stage 1: mem = zH @ W_mem   (K=512;  W_mem = 4 MiB)
    // grid (4, 32): 128 blocks, KCHUNK=16
    {
        dim3 grd(D_MODEL / (256 * 2), D_H / 16);
        gemv4_splitk_v2<16><<<grd, blk, 0, stream>>>(zH, W_mem, mem, D_H, D_MODEL);
    }
    // Stage 2: V = mem @ W_v      (K=2048; W_v = 16 MiB)
    // grid (4, 64): 256 blocks (1/CU), KCHUNK=32
    {
        dim3 grd(D_MODEL / (256 * 2), D_MODEL / 32);
        gemv4_splitk_v2<32><<<grd, blk, 0, stream>>>(mem, W_v, V, D_MODEL, D_MODEL);
    }
    // Stage 3: r = V @ W_o        (K=2048; W_o = 16 MiB)
    {
        dim3 grd(D_MODEL / (256 * 2), D_MODEL / 32);
        gemv4_splitk_v2<32><<<grd, blk, 0, stream>>>(V, W_o, r, D_MODEL, D_MODEL);
    }
    // Stage 4: out = lh + sigmoid(gate) * r  (broadcast over T; 268 MB stream)
    {
        long nchunks = (long)B_ * T_ * D_MODEL / 4;  // 8,388,608 vfloat4
        dim3 grd(2048);                              // grid-stride, 16 iters/thread
        broadcast_add<<<grd, blk, 0, stream>>>(
            (const vfloat4*)lh, r, gate, (vfloat4*)out, nchunks);
    }
}